// Round 6
// baseline (817.395 us; speedup 1.0000x reference)
//
#include <hip/hip_runtime.h>

#define EMB 128
#define EDGE 32
#define STEPS 3

typedef short bf8s __attribute__((ext_vector_type(8)));
typedef float f32x4 __attribute__((ext_vector_type(4)));
typedef unsigned short u16x4 __attribute__((ext_vector_type(4)));

__device__ __forceinline__ float lrelu(float v) { return v > 0.0f ? v : 0.01f * v; }
__device__ __forceinline__ unsigned short f2bf(float f) {
    unsigned u = __float_as_uint(f);
    u += 0x7fffu + ((u >> 16) & 1u);
    return (unsigned short)(u >> 16);
}
__device__ __forceinline__ float bf2f(unsigned short s) {
    return __uint_as_float(((unsigned)s) << 16);
}

// ---------------- CSR build ----------------
__global__ void k_hist(const int* __restrict__ dst, int E, int* __restrict__ deg) {
    int e = blockIdx.x * 256 + threadIdx.x;
    if (e < E) atomicAdd(&deg[dst[e]], 1);
}

__global__ void k_scan1(const int* __restrict__ deg, int N, int* __restrict__ rowptr,
                        int* __restrict__ bsums) {
    __shared__ int s[256];
    int t = threadIdx.x;
    int i = blockIdx.x * 256 + t;
    int v = (i < N) ? deg[i] : 0;
    s[t] = v;
    __syncthreads();
#pragma unroll
    for (int off = 1; off < 256; off <<= 1) {
        int x = (t >= off) ? s[t - off] : 0;
        __syncthreads();
        s[t] += x;
        __syncthreads();
    }
    if (i < N) rowptr[i] = s[t] - v;
    if (t == 255) bsums[blockIdx.x] = s[255];
}

__global__ void k_scan2(int* __restrict__ bsums, int NB) {
    __shared__ int s[256];
    __shared__ int carry;
    int t = threadIdx.x;
    if (t == 0) carry = 0;
    __syncthreads();
    for (int base = 0; base < NB; base += 256) {
        int i = base + t;
        int v = (i < NB) ? bsums[i] : 0;
        s[t] = v;
        __syncthreads();
#pragma unroll
        for (int off = 1; off < 256; off <<= 1) {
            int x = (t >= off) ? s[t - off] : 0;
            __syncthreads();
            s[t] += x;
            __syncthreads();
        }
        int excl = s[t] - v + carry;
        if (i < NB) bsums[i] = excl;
        int tot = s[255];
        __syncthreads();
        if (t == 0) carry += tot;
        __syncthreads();
    }
}

__global__ void k_scan3(int* __restrict__ rowptr, const int* __restrict__ bsums, int N, int E) {
    int i = blockIdx.x * 256 + threadIdx.x;
    if (i < N) rowptr[i] += bsums[i >> 8];
    if (i == 0) rowptr[N] = E;
}

__global__ void k_fill(const int* __restrict__ src, const int* __restrict__ dst, int E,
                       int* __restrict__ cursor, int2* __restrict__ slot) {
    int e = blockIdx.x * 256 + threadIdx.x;
    if (e < E) {
        int d = dst[e];
        int p = atomicAdd(&cursor[d], 1);
        slot[p] = make_int2(src[e], e);
    }
}

__global__ void k_gstart(const int* __restrict__ batch, int N, int G, int* __restrict__ gstart) {
    int g = blockIdx.x * blockDim.x + threadIdx.x;
    if (g > G) return;
    int lo = 0, hi = N;
    while (lo < hi) {
        int mid = (lo + hi) >> 1;
        if (batch[mid] < g) lo = mid + 1; else hi = mid;
    }
    gstart[g] = lo;
}

// ---------------- weight prepack: fp32 row-major -> bf16 B-fragment order ----------------
// B-frag (16x16x32): lane holds col n=lane&15, k=(lane>>4)*8+j.
// Per 128x128 unit: [kc(4)][ctile(8)][lane(64)][j(8)] = 16384 ushort.
// Units/step: 0=Wm_x 1=Wm_e(32 rows, kc=0 only; also serves as Wm_e^T A-frag,
// ctile==rowtile by index symmetry) 2=Wa_x 3=Wa_agg 4=Wfeat.
__global__ __launch_bounds__(256) void k_wpack(const float* __restrict__ Wm,
                                               const float* __restrict__ Wa,
                                               const float* __restrict__ Wfeat,
                                               unsigned short* __restrict__ wpack) {
    int gid = blockIdx.x * 256 + threadIdx.x;
    int unit = gid >> 14;
    int e = gid & 16383;
    int s = unit / 5, u = unit % 5;
    const float* src; int rows;
    switch (u) {
        case 0: src = Wm + (size_t)s * 160 * EMB;             rows = 128; break;
        case 1: src = Wm + (size_t)s * 160 * EMB + 128 * EMB; rows = 32;  break;
        case 2: src = Wa + (size_t)s * 384 * EMB;             rows = 128; break;
        case 3: src = Wa + (size_t)s * 384 * EMB + 256 * EMB; rows = 128; break;
        default: src = Wfeat + (size_t)s * EMB * EMB;         rows = 128; break;
    }
    int k = e >> 7, n = e & 127;
    if (k >= rows) return;
    unsigned short b = f2bf(src[(size_t)k * EMB + n]);
    int kc = k >> 5, c = n >> 4, lane = (n & 15) | (((k & 31) >> 3) << 4), j = k & 7;
    wpack[(size_t)unit * 16384 + ((size_t)(kc * 8 + c) * 64 + lane) * 8 + j] = b;
}

// ---------------- MFMA GEMM core: 64 rows x 128 cols, K=128 ----------------
__device__ __forceinline__ void stageA(const float* __restrict__ A, int row0, int N,
                                       unsigned short* lA, int tid) {
#pragma unroll
    for (int i = 0; i < 8; ++i) {
        int idx = tid + i * 256;
        int m = idx >> 5, c4 = idx & 31, k0 = c4 * 4;
        float4 v = make_float4(0.f, 0.f, 0.f, 0.f);
        if (row0 + m < N) v = ((const float4*)(A + (size_t)(row0 + m) * EMB))[c4];
        int kc = k0 >> 5, oct = (k0 & 31) >> 3, j0 = k0 & 7;
        int lane = (m & 15) | (oct << 4), rt = m >> 4;
        u16x4 pk = { f2bf(v.x), f2bf(v.y), f2bf(v.z), f2bf(v.w) };
        *(u16x4*)&lA[(((kc * 4 + rt) * 64 + lane) * 8) + j0] = pk;
    }
}
__device__ __forceinline__ void stageA_bf(const unsigned short* __restrict__ A, int row0, int N,
                                          unsigned short* lA, int tid) {
#pragma unroll
    for (int i = 0; i < 4; ++i) {
        int idx = tid + i * 256;
        int m = idx >> 4, o = idx & 15;
        int4 v = make_int4(0, 0, 0, 0);
        if (row0 + m < N) v = ((const int4*)(A + (size_t)(row0 + m) * EMB))[o];
        int kc = o >> 2, oct = o & 3;
        int lane = (m & 15) | (oct << 4), rt = m >> 4;
        *(int4*)&lA[((kc * 4 + rt) * 64 + lane) * 8] = v;
    }
}
__device__ __forceinline__ void stageB(const unsigned short* __restrict__ Bp,
                                       unsigned short* lB, int tid) {
#pragma unroll
    for (int i = 0; i < 8; ++i) {
        int idx = tid + i * 256;
        ((int4*)lB)[idx] = ((const int4*)Bp)[idx];
    }
}
__device__ __forceinline__ void mfma128(const unsigned short* lA, const unsigned short* lB,
                                        f32x4 acc[8], int wv, int lane) {
#pragma unroll
    for (int kc = 0; kc < 4; ++kc) {
        bf8s a = *(const bf8s*)&lA[((kc * 4 + wv) * 64 + lane) * 8];
#pragma unroll
        for (int c = 0; c < 8; ++c) {
            bf8s b = *(const bf8s*)&lB[((kc * 8 + c) * 64 + lane) * 8];
            acc[c] = __builtin_amdgcn_mfma_f32_16x16x32_bf16(a, b, acc[c], 0, 0, 0);
        }
    }
}

// h16 = bf16(x @ Wm_x + bm)
__global__ __launch_bounds__(256) void k_gemm_bias(const float* __restrict__ A,
                                                   const unsigned short* __restrict__ Bp,
                                                   const float* __restrict__ bias,
                                                   unsigned short* __restrict__ C, int N) {
    __shared__ unsigned short lA[8192];
    __shared__ unsigned short lB[16384];
    int tid = threadIdx.x, wv = tid >> 6, lane = tid & 63;
    int row0 = blockIdx.x * 64;
    stageA(A, row0, N, lA, tid);
    stageB(Bp, lB, tid);
    __syncthreads();
    f32x4 acc[8];
#pragma unroll
    for (int c = 0; c < 8; ++c) acc[c] = (f32x4){0.f, 0.f, 0.f, 0.f};
    mfma128(lA, lB, acc, wv, lane);
    int li = lane & 15, quad = lane >> 4;
#pragma unroll
    for (int c = 0; c < 8; ++c) {
        int col = c * 16 + li;
        float b = bias[col];
#pragma unroll
        for (int rr = 0; rr < 4; ++rr) {
            int m = row0 + wv * 16 + quad * 4 + rr;
            if (m < N) C[(size_t)m * EMB + col] = f2bf(acc[c][rr] + b);
        }
    }
}

// x_out = lrelu(x@Wa_x + agg16@Wa_agg + gb[batch]) + x ; fused gate = x_out.wg + bg
__global__ __launch_bounds__(256) void k_gemm_node(const float* __restrict__ x,
                                                   const unsigned short* __restrict__ agg16,
                                                   const unsigned short* __restrict__ BpX,
                                                   const unsigned short* __restrict__ BpA,
                                                   const float* __restrict__ gb,
                                                   const int* __restrict__ batch,
                                                   float* __restrict__ xout,
                                                   const float* __restrict__ wg,
                                                   const float* __restrict__ bg,
                                                   float* __restrict__ gate, int N) {
    __shared__ unsigned short lA[8192];
    __shared__ unsigned short lB[16384];
    int tid = threadIdx.x, wv = tid >> 6, lane = tid & 63;
    int row0 = blockIdx.x * 64;
    stageA(x, row0, N, lA, tid);
    stageB(BpX, lB, tid);
    __syncthreads();
    f32x4 acc[8];
#pragma unroll
    for (int c = 0; c < 8; ++c) acc[c] = (f32x4){0.f, 0.f, 0.f, 0.f};
    mfma128(lA, lB, acc, wv, lane);
    __syncthreads();
    stageA_bf(agg16, row0, N, lA, tid);
    stageB(BpA, lB, tid);
    __syncthreads();
    mfma128(lA, lB, acc, wv, lane);
    int li = lane & 15, quad = lane >> 4;
    float gpart[4] = {0.f, 0.f, 0.f, 0.f};
#pragma unroll
    for (int c = 0; c < 8; ++c) {
        int col = c * 16 + li;
        float wgc = wg[col];
#pragma unroll
        for (int rr = 0; rr < 4; ++rr) {
            int m = row0 + wv * 16 + quad * 4 + rr;
            if (m < N) {
                int g = batch[m];
                float b = gb[(size_t)g * EMB + col];
                float res = x[(size_t)m * EMB + col];
                float v = lrelu(acc[c][rr] + b) + res;
                xout[(size_t)m * EMB + col] = v;
                gpart[rr] = fmaf(v, wgc, gpart[rr]);
            }
        }
    }
#pragma unroll
    for (int rr = 0; rr < 4; ++rr) {
#pragma unroll
        for (int off = 1; off < 16; off <<= 1)
            gpart[rr] += __shfl_xor(gpart[rr], off, 64);
    }
    if (li == 0) {
        float b0 = bg[0];
#pragma unroll
        for (int rr = 0; rr < 4; ++rr) {
            int m = row0 + wv * 16 + quad * 4 + rr;
            if (m < N) gate[m] = gpart[rr] + b0;
        }
    }
}

// feat16 = bf16(alpha * lrelu(x@Wfeat + bfeat))
__global__ __launch_bounds__(256) void k_gemm_feat(const float* __restrict__ A,
                                                   const unsigned short* __restrict__ Bp,
                                                   const float* __restrict__ bias,
                                                   const float* __restrict__ gate,
                                                   const float* __restrict__ gmax,
                                                   const float* __restrict__ denom,
                                                   const int* __restrict__ batch,
                                                   unsigned short* __restrict__ C, int N) {
    __shared__ unsigned short lA[8192];
    __shared__ unsigned short lB[16384];
    int tid = threadIdx.x, wv = tid >> 6, lane = tid & 63;
    int row0 = blockIdx.x * 64;
    stageA(A, row0, N, lA, tid);
    stageB(Bp, lB, tid);
    __syncthreads();
    f32x4 acc[8];
#pragma unroll
    for (int c = 0; c < 8; ++c) acc[c] = (f32x4){0.f, 0.f, 0.f, 0.f};
    mfma128(lA, lB, acc, wv, lane);
    int li = lane & 15, quad = lane >> 4;
    float alpha[4];
#pragma unroll
    for (int rr = 0; rr < 4; ++rr) {
        int m = row0 + wv * 16 + quad * 4 + rr;
        if (m < N) {
            int g = batch[m];
            alpha[rr] = __expf(gate[m] - gmax[g]) / denom[g];
        } else alpha[rr] = 0.f;
    }
#pragma unroll
    for (int c = 0; c < 8; ++c) {
        int col = c * 16 + li;
        float b = bias[col];
#pragma unroll
        for (int rr = 0; rr < 4; ++rr) {
            int m = row0 + wv * 16 + quad * 4 + rr;
            if (m < N) C[(size_t)m * EMB + col] = f2bf(alpha[rr] * lrelu(acc[c][rr] + b));
        }
    }
}

// ---------------- fused edge-message MFMA + segment-max (TRANSPOSED) ----------------
// One wave per node; 16-edge batches. emsg^T[128ch x 16e] = Wm_e^T(A, LDS) @
// ea^T(B, regs). In C-layout col = lane&15 = EDGE index, so each lane owns the
// edge whose slot it loaded: h-add is 8 contiguous 8B loads of the lane's own
// h[src] row (no shfl, no scalar gathers; R5's C-layout version needed 32
// scalar 2B gathers/batch -> VMEM-issue-bound). Max accumulates per-lane
// across batches; one cross-li shfl reduction per node at the end.
__global__ __launch_bounds__(256) void k_fagg(const unsigned short* __restrict__ h,
                                              const float* __restrict__ ea,
                                              const int2* __restrict__ slot,
                                              const int* __restrict__ rowptr,
                                              const unsigned short* __restrict__ Bp,
                                              unsigned short* __restrict__ agg, int N) {
    __shared__ unsigned short lA[4096];   // Wm_e^T A-frag: [t(8)][lane(64)][j(8)]
    int tid = threadIdx.x;
    ((int4*)lA)[tid]       = ((const int4*)Bp)[tid];
    ((int4*)lA)[tid + 256] = ((const int4*)Bp)[tid + 256];
    __syncthreads();
    int wv = tid >> 6, lane = tid & 63;
    int n = blockIdx.x * 4 + wv;
    if (n >= N) return;
    int li = lane & 15, oct = lane >> 4;
    int r0 = rowptr[n], r1 = rowptr[n + 1], deg = r1 - r0;

    f32x4 vm[8];
#pragma unroll
    for (int t = 0; t < 8; ++t)
        vm[t] = (f32x4){-__builtin_inff(), -__builtin_inff(),
                        -__builtin_inff(), -__builtin_inff()};

    for (int b = 0; b < deg; b += 16) {
        int p = r0 + b + li;
        bool valid = (b + li) < deg;
        if (p > r1 - 1) p = r1 - 1;
        int2 sl = slot[p];
        // B-frag: this lane's edge (b+li), k = oct*8 + j
        const float4* ear = (const float4*)(ea + (size_t)sl.y * EDGE);
        float4 v0 = ear[oct * 2], v1 = ear[oct * 2 + 1];
        bf8s bfrag;
        bfrag[0] = (short)f2bf(v0.x); bfrag[1] = (short)f2bf(v0.y);
        bfrag[2] = (short)f2bf(v0.z); bfrag[3] = (short)f2bf(v0.w);
        bfrag[4] = (short)f2bf(v1.x); bfrag[5] = (short)f2bf(v1.y);
        bfrag[6] = (short)f2bf(v1.z); bfrag[7] = (short)f2bf(v1.w);
        // h row of this lane's own src: 8 contiguous 8B segments
        u16x4 hseg[8];
#pragma unroll
        for (int t = 0; t < 8; ++t)
            hseg[t] = *(const u16x4*)&h[(size_t)sl.x * EMB + t * 16 + oct * 4];
#pragma unroll
        for (int t = 0; t < 8; ++t) {
            bf8s a = *(const bf8s*)&lA[(t * 64 + lane) * 8];
            f32x4 acc = (f32x4){0.f, 0.f, 0.f, 0.f};
            acc = __builtin_amdgcn_mfma_f32_16x16x32_bf16(a, bfrag, acc, 0, 0, 0);
            if (valid) {
#pragma unroll
                for (int rr = 0; rr < 4; ++rr) {
                    float v = lrelu(bf2f(hseg[t][rr]) + acc[rr]);
                    vm[t][rr] = fmaxf(vm[t][rr], v);
                }
            }
        }
    }
    // reduce max over the 16 li-lanes (edge dimension)
#pragma unroll
    for (int t = 0; t < 8; ++t) {
#pragma unroll
        for (int rr = 0; rr < 4; ++rr) {
            float v = vm[t][rr];
            v = fmaxf(v, __shfl_xor(v, 1, 64));
            v = fmaxf(v, __shfl_xor(v, 2, 64));
            v = fmaxf(v, __shfl_xor(v, 4, 64));
            v = fmaxf(v, __shfl_xor(v, 8, 64));
            vm[t][rr] = v;
        }
    }
    // mux: lane (li,oct) writes channels (li>>2)*16+oct*4+(li&3) and +64
    float va = 0.f, vb = 0.f;
#pragma unroll
    for (int t = 0; t < 4; ++t) {
#pragma unroll
        for (int rr = 0; rr < 4; ++rr) {
            if (li == t * 4 + rr) { va = vm[t][rr]; vb = vm[t + 4][rr]; }
        }
    }
    if (deg == 0) { va = 0.f; vb = 0.f; }
    size_t base = (size_t)n * EMB + (li >> 2) * 16 + oct * 4 + (li & 3);
    agg[base]      = f2bf(va);
    agg[base + 64] = f2bf(vb);
}

// ---------------- small per-graph kernels ----------------
__global__ __launch_bounds__(128) void k_gb(const float* __restrict__ xg,
                                            const float* __restrict__ WaG,
                                            const float* __restrict__ ba,
                                            float* __restrict__ gb) {
    int g = blockIdx.x, c = threadIdx.x;
    __shared__ float row[EMB];
    row[c] = xg[(size_t)g * EMB + c];
    __syncthreads();
    float acc = ba[c];
#pragma unroll 8
    for (int k = 0; k < EMB; ++k) acc = fmaf(row[k], WaG[(size_t)k * EMB + c], acc);
    gb[(size_t)g * EMB + c] = acc;
}

__global__ __launch_bounds__(256) void k_gseg(const float* __restrict__ gate,
                                              const int* __restrict__ gstart,
                                              float* __restrict__ gmax,
                                              float* __restrict__ denom) {
    int g = blockIdx.x;
    int s0 = gstart[g], s1 = gstart[g + 1];
    __shared__ float red[256];
    int t = threadIdx.x;
    float mx = -__builtin_inff();
    for (int i = s0 + t; i < s1; i += 256) mx = fmaxf(mx, gate[i]);
    red[t] = mx;
    __syncthreads();
#pragma unroll
    for (int off = 128; off; off >>= 1) {
        if (t < off) red[t] = fmaxf(red[t], red[t + off]);
        __syncthreads();
    }
    float m = red[0];
    __syncthreads();
    float sum = 0.f;
    for (int i = s0 + t; i < s1; i += 256) sum += __expf(gate[i] - m);
    red[t] = sum;
    __syncthreads();
#pragma unroll
    for (int off = 128; off; off >>= 1) {
        if (t < off) red[t] += red[t + off];
        __syncthreads();
    }
    if (t == 0) {
        gmax[g] = (s1 > s0) ? m : 0.f;
        denom[g] = red[0];
    }
}

__global__ __launch_bounds__(512) void k_pool(const unsigned short* __restrict__ feat,
                                              const int* __restrict__ gstart,
                                              float* __restrict__ pooled) {
    int g = blockIdx.x;
    int c = threadIdx.x & 127;
    int r = threadIdx.x >> 7;
    int s0 = gstart[g], s1 = gstart[g + 1];
    float s = 0.f;
    for (int i = s0 + r; i < s1; i += 4) s += bf2f(feat[(size_t)i * EMB + c]);
    __shared__ float red[512];
    red[threadIdx.x] = s;
    __syncthreads();
    if (threadIdx.x < 256) red[threadIdx.x] += red[threadIdx.x + 256];
    __syncthreads();
    if (threadIdx.x < 128)
        pooled[(size_t)g * EMB + threadIdx.x] = red[threadIdx.x] + red[threadIdx.x + 128];
}

__global__ __launch_bounds__(128) void k_xg(const float* __restrict__ pooled,
                                            const float* __restrict__ xg,
                                            const float* __restrict__ Wt,
                                            const float* __restrict__ bt,
                                            float* __restrict__ xg_out) {
    int g = blockIdx.x, c = threadIdx.x;
    __shared__ float row[256];
    row[c] = pooled[(size_t)g * EMB + c];
    row[c + 128] = xg[(size_t)g * EMB + c];
    __syncthreads();
    float acc = bt[c];
#pragma unroll 8
    for (int k = 0; k < 256; ++k) acc = fmaf(row[k], Wt[(size_t)k * EMB + c], acc);
    xg_out[(size_t)g * EMB + c] = lrelu(acc) + row[c + 128];
}

// ---------------- launch ----------------
extern "C" void kernel_launch(void* const* d_in, const int* in_sizes, int n_in,
                              void* d_out, int out_size, void* d_ws, size_t ws_size,
                              hipStream_t stream) {
    const float* x0    = (const float*)d_in[0];
    const float* ea    = (const float*)d_in[1];
    const float* Wm    = (const float*)d_in[2];
    const float* bm    = (const float*)d_in[3];
    const float* Wa    = (const float*)d_in[4];
    const float* ba    = (const float*)d_in[5];
    const float* Wgate = (const float*)d_in[6];
    const float* bgate = (const float*)d_in[7];
    const float* Wfeat = (const float*)d_in[8];
    const float* bfeat = (const float*)d_in[9];
    const float* Wt    = (const float*)d_in[10];
    const float* bt    = (const float*)d_in[11];
    const int*   eidx  = (const int*)d_in[12];
    const int*   batch = (const int*)d_in[13];

    int N = in_sizes[0] / EMB;
    int E = in_sizes[1] / EDGE;
    int G = in_sizes[15];

    char* w = (char*)d_ws;
    auto alloc = [&](size_t bytes) {
        char* p = w;
        w += (bytes + 255) & ~(size_t)255;
        return p;
    };
    unsigned short* h16   = (unsigned short*)alloc((size_t)N * EMB * 2);
    unsigned short* agg16 = (unsigned short*)alloc((size_t)N * EMB * 2);
    unsigned short* ft16  = (unsigned short*)alloc((size_t)N * EMB * 2);
    float* gate   = (float*)alloc((size_t)N * 4);
    float* gb     = (float*)alloc((size_t)G * EMB * 4);
    float* pooled = (float*)alloc((size_t)G * EMB * 4);
    float* gmax   = (float*)alloc((size_t)G * 4);
    float* denom  = (float*)alloc((size_t)G * 4);
    float* xg_a   = (float*)alloc((size_t)G * EMB * 4);
    float* xg_b   = (float*)alloc((size_t)G * EMB * 4);
    int* deg      = (int*)alloc((size_t)N * 4);
    int* rowptr   = (int*)alloc((size_t)(N + 1) * 4);
    int* cursor   = (int*)alloc((size_t)N * 4);
    int2* slot    = (int2*)alloc((size_t)E * 8);
    int* gstart   = (int*)alloc((size_t)(G + 1) * 4);
    int* bsums    = (int*)alloc(1024 * 4);
    unsigned short* wpack = (unsigned short*)alloc((size_t)15 * 16384 * 2);

    const int* esrc = eidx;
    const int* edst = eidx + E;
    int ebl = (E + 255) / 256;
    int NB  = (N + 255) / 256;

    hipMemsetAsync(deg, 0, (size_t)N * 4, stream);
    k_hist<<<ebl, 256, 0, stream>>>(edst, E, deg);
    k_scan1<<<NB, 256, 0, stream>>>(deg, N, rowptr, bsums);
    k_scan2<<<1, 256, 0, stream>>>(bsums, NB);
    k_scan3<<<NB, 256, 0, stream>>>(rowptr, bsums, N, E);
    hipMemcpyAsync(cursor, rowptr, (size_t)N * 4, hipMemcpyDeviceToDevice, stream);
    k_fill<<<ebl, 256, 0, stream>>>(esrc, edst, E, cursor, slot);
    k_gstart<<<(G + 256) / 256, 256, 0, stream>>>(batch, N, G, gstart);
    hipMemsetAsync(xg_a, 0, (size_t)G * EMB * 4, stream);
    k_wpack<<<960, 256, 0, stream>>>(Wm, Wa, Wfeat, wpack);

    int gemm_blocks = (N + 63) / 64;
    int fagg_blocks = (N + 3) / 4;

    const float* x_in = x0;
    float* xg_cur = xg_a;
    float* xg_nxt = xg_b;

    for (int s = 0; s < STEPS; ++s) {
        const unsigned short* wp = wpack + (size_t)s * 5 * 16384;
        float* x_out = (s == STEPS - 1) ? (float*)d_out : (float*)x_in;

        k_gemm_bias<<<gemm_blocks, 256, 0, stream>>>(x_in, wp + 0 * 16384, bm + s * EMB,
                                                     h16, N);
        k_fagg<<<fagg_blocks, 256, 0, stream>>>(h16, ea, slot, rowptr, wp + 1 * 16384,
                                                agg16, N);
        k_gb<<<G, 128, 0, stream>>>(xg_cur, Wa + (size_t)s * 384 * EMB + 128 * EMB,
                                    ba + s * EMB, gb);
        k_gemm_node<<<gemm_blocks, 256, 0, stream>>>(x_in, agg16, wp + 2 * 16384,
                                                     wp + 3 * 16384, gb, batch, x_out,
                                                     Wgate + s * EMB, bgate + s, gate, N);
        k_gseg<<<G, 256, 0, stream>>>(gate, gstart, gmax, denom);
        k_gemm_feat<<<gemm_blocks, 256, 0, stream>>>(x_out, wp + 4 * 16384, bfeat + s * EMB,
                                                     gate, gmax, denom, batch, ft16, N);
        k_pool<<<G, 512, 0, stream>>>(ft16, gstart, pooled);
        k_xg<<<G, 128, 0, stream>>>(pooled, xg_cur, Wt + (size_t)s * 256 * EMB,
                                    bt + s * EMB, xg_nxt);

        x_in = x_out;
        float* tmp = xg_cur; xg_cur = xg_nxt; xg_nxt = tmp;
    }

    hipMemcpyAsync((float*)d_out + (size_t)N * EMB, xg_cur, (size_t)G * EMB * 4,
                   hipMemcpyDeviceToDevice, stream);
}

// Round 7
// 685.079 us; speedup vs baseline: 1.1931x; 1.1931x over previous
//
#include <hip/hip_runtime.h>
#include <hip/hip_bf16.h>

#define EMB 128
#define EDGE 32
#define STEPS 3

typedef short bf8s __attribute__((ext_vector_type(8)));
typedef float f32x4 __attribute__((ext_vector_type(4)));
typedef unsigned short u16x4 __attribute__((ext_vector_type(4)));

__device__ __forceinline__ float lrelu(float v) { return v > 0.0f ? v : 0.01f * v; }
__device__ __forceinline__ unsigned short f2bf(float f) {
    unsigned u = __float_as_uint(f);
    u += 0x7fffu + ((u >> 16) & 1u);
    return (unsigned short)(u >> 16);
}
__device__ __forceinline__ float bf2f(unsigned short s) {
    return __uint_as_float(((unsigned)s) << 16);
}
// packed fp32x2 -> bf16x2 (v_cvt_pk_bf16_f32 on gfx950)
__device__ __forceinline__ unsigned pk2bf(float x, float y) {
    __hip_bfloat162 h = __float22bfloat162_rn(make_float2(x, y));
    return *(unsigned*)&h;
}

// ---------------- CSR build ----------------
__global__ void k_hist(const int* __restrict__ dst, int E, int* __restrict__ deg) {
    int e = blockIdx.x * 256 + threadIdx.x;
    if (e < E) atomicAdd(&deg[dst[e]], 1);
}

__global__ void k_scan1(const int* __restrict__ deg, int N, int* __restrict__ rowptr,
                        int* __restrict__ bsums) {
    __shared__ int s[256];
    int t = threadIdx.x;
    int i = blockIdx.x * 256 + t;
    int v = (i < N) ? deg[i] : 0;
    s[t] = v;
    __syncthreads();
#pragma unroll
    for (int off = 1; off < 256; off <<= 1) {
        int x = (t >= off) ? s[t - off] : 0;
        __syncthreads();
        s[t] += x;
        __syncthreads();
    }
    if (i < N) rowptr[i] = s[t] - v;
    if (t == 255) bsums[blockIdx.x] = s[255];
}

__global__ void k_scan2(int* __restrict__ bsums, int NB) {
    __shared__ int s[256];
    __shared__ int carry;
    int t = threadIdx.x;
    if (t == 0) carry = 0;
    __syncthreads();
    for (int base = 0; base < NB; base += 256) {
        int i = base + t;
        int v = (i < NB) ? bsums[i] : 0;
        s[t] = v;
        __syncthreads();
#pragma unroll
        for (int off = 1; off < 256; off <<= 1) {
            int x = (t >= off) ? s[t - off] : 0;
            __syncthreads();
            s[t] += x;
            __syncthreads();
        }
        int excl = s[t] - v + carry;
        if (i < NB) bsums[i] = excl;
        int tot = s[255];
        __syncthreads();
        if (t == 0) carry += tot;
        __syncthreads();
    }
}

__global__ void k_scan3(int* __restrict__ rowptr, const int* __restrict__ bsums, int N, int E) {
    int i = blockIdx.x * 256 + threadIdx.x;
    if (i < N) rowptr[i] += bsums[i >> 8];
    if (i == 0) rowptr[N] = E;
}

__global__ void k_fill(const int* __restrict__ src, const int* __restrict__ dst, int E,
                       int* __restrict__ cursor, int2* __restrict__ slot) {
    int e = blockIdx.x * 256 + threadIdx.x;
    if (e < E) {
        int d = dst[e];
        int p = atomicAdd(&cursor[d], 1);
        slot[p] = make_int2(src[e], e);
    }
}

__global__ void k_gstart(const int* __restrict__ batch, int N, int G, int* __restrict__ gstart) {
    int g = blockIdx.x * blockDim.x + threadIdx.x;
    if (g > G) return;
    int lo = 0, hi = N;
    while (lo < hi) {
        int mid = (lo + hi) >> 1;
        if (batch[mid] < g) lo = mid + 1; else hi = mid;
    }
    gstart[g] = lo;
}

// ---------------- weight prepack: fp32 row-major -> bf16 B-fragment order ----------------
__global__ __launch_bounds__(256) void k_wpack(const float* __restrict__ Wm,
                                               const float* __restrict__ Wa,
                                               const float* __restrict__ Wfeat,
                                               unsigned short* __restrict__ wpack) {
    int gid = blockIdx.x * 256 + threadIdx.x;
    int unit = gid >> 14;
    int e = gid & 16383;
    int s = unit / 5, u = unit % 5;
    const float* src; int rows;
    switch (u) {
        case 0: src = Wm + (size_t)s * 160 * EMB;             rows = 128; break;
        case 1: src = Wm + (size_t)s * 160 * EMB + 128 * EMB; rows = 32;  break;
        case 2: src = Wa + (size_t)s * 384 * EMB;             rows = 128; break;
        case 3: src = Wa + (size_t)s * 384 * EMB + 256 * EMB; rows = 128; break;
        default: src = Wfeat + (size_t)s * EMB * EMB;         rows = 128; break;
    }
    int k = e >> 7, n = e & 127;
    if (k >= rows) return;
    unsigned short b = f2bf(src[(size_t)k * EMB + n]);
    int kc = k >> 5, c = n >> 4, lane = (n & 15) | (((k & 31) >> 3) << 4), j = k & 7;
    wpack[(size_t)unit * 16384 + ((size_t)(kc * 8 + c) * 64 + lane) * 8 + j] = b;
}

// ---------------- MFMA GEMM core: 64 rows x 128 cols, K=128 ----------------
// A-fragments loaded DIRECTLY global->registers (no LDS roundtrip/barrier):
// lane (li,oct) of wave wv owns row row0+wv*16+li, k-chunk kc -> cols
// kc*32+oct*8..+7. Rows >= N clamped (garbage masked in epilogue).
__device__ __forceinline__ void loadAx(const float* __restrict__ A, int row0, int wv,
                                       int lane, int N, bf8s af[4]) {
    int li = lane & 15, oct = lane >> 4;
    int m = row0 + wv * 16 + li;
    if (m >= N) m = N - 1;
    const float4* xr = (const float4*)(A + (size_t)m * EMB);
#pragma unroll
    for (int kc = 0; kc < 4; ++kc) {
        float4 a0 = xr[kc * 8 + oct * 2];
        float4 a1 = xr[kc * 8 + oct * 2 + 1];
        union { bf8s v; unsigned u[4]; } c;
        c.u[0] = pk2bf(a0.x, a0.y);
        c.u[1] = pk2bf(a0.z, a0.w);
        c.u[2] = pk2bf(a1.x, a1.y);
        c.u[3] = pk2bf(a1.z, a1.w);
        af[kc] = c.v;
    }
}
// bf16 row-major source
__device__ __forceinline__ void loadAa(const unsigned short* __restrict__ A16, int row0,
                                       int wv, int lane, int N, bf8s af[4]) {
    int li = lane & 15, oct = lane >> 4;
    int m = row0 + wv * 16 + li;
    if (m >= N) m = N - 1;
    const bf8s* ar = (const bf8s*)(A16 + (size_t)m * EMB);
#pragma unroll
    for (int kc = 0; kc < 4; ++kc) af[kc] = ar[kc * 4 + oct];
}
__device__ __forceinline__ void stageB(const unsigned short* __restrict__ Bp,
                                       unsigned short* lB, int tid) {
#pragma unroll
    for (int i = 0; i < 8; ++i) {
        int idx = tid + i * 256;
        ((int4*)lB)[idx] = ((const int4*)Bp)[idx];
    }
}
__device__ __forceinline__ void mfma128r(const bf8s af[4], const unsigned short* lB,
                                         f32x4 acc[8], int lane) {
#pragma unroll
    for (int kc = 0; kc < 4; ++kc) {
#pragma unroll
        for (int c = 0; c < 8; ++c) {
            bf8s b = *(const bf8s*)&lB[((kc * 8 + c) * 64 + lane) * 8];
            acc[c] = __builtin_amdgcn_mfma_f32_16x16x32_bf16(af[kc], b, acc[c], 0, 0, 0);
        }
    }
}

// h16 = bf16(x @ Wm_x + bm)
__global__ __launch_bounds__(256) void k_gemm_bias(const float* __restrict__ A,
                                                   const unsigned short* __restrict__ Bp,
                                                   const float* __restrict__ bias,
                                                   unsigned short* __restrict__ C, int N) {
    __shared__ unsigned short lB[16384];
    int tid = threadIdx.x, wv = tid >> 6, lane = tid & 63;
    int row0 = blockIdx.x * 64;
    stageB(Bp, lB, tid);
    bf8s af[4];
    loadAx(A, row0, wv, lane, N, af);
    __syncthreads();
    f32x4 acc[8];
#pragma unroll
    for (int c = 0; c < 8; ++c) acc[c] = (f32x4){0.f, 0.f, 0.f, 0.f};
    mfma128r(af, lB, acc, lane);
    int li = lane & 15, quad = lane >> 4;
#pragma unroll
    for (int c = 0; c < 8; ++c) {
        int col = c * 16 + li;
        float b = bias[col];
#pragma unroll
        for (int rr = 0; rr < 4; ++rr) {
            int m = row0 + wv * 16 + quad * 4 + rr;
            if (m < N) C[(size_t)m * EMB + col] = f2bf(acc[c][rr] + b);
        }
    }
}

// x_out = lrelu(x@Wa_x + agg16@Wa_agg + gb[batch]) + x ; fused gate = x_out.wg + bg
__global__ __launch_bounds__(256) void k_gemm_node(const float* __restrict__ x,
                                                   const unsigned short* __restrict__ agg16,
                                                   const unsigned short* __restrict__ BpX,
                                                   const unsigned short* __restrict__ BpA,
                                                   const float* __restrict__ gb,
                                                   const int* __restrict__ batch,
                                                   float* __restrict__ xout,
                                                   const float* __restrict__ wg,
                                                   const float* __restrict__ bg,
                                                   float* __restrict__ gate, int N) {
    __shared__ unsigned short lB[16384];
    int tid = threadIdx.x, wv = tid >> 6, lane = tid & 63;
    int row0 = blockIdx.x * 64;
    stageB(BpX, lB, tid);
    bf8s af[4];
    loadAx(x, row0, wv, lane, N, af);
    __syncthreads();
    f32x4 acc[8];
#pragma unroll
    for (int c = 0; c < 8; ++c) acc[c] = (f32x4){0.f, 0.f, 0.f, 0.f};
    mfma128r(af, lB, acc, lane);
    __syncthreads();
    stageB(BpA, lB, tid);
    loadAa(agg16, row0, wv, lane, N, af);
    __syncthreads();
    mfma128r(af, lB, acc, lane);
    int li = lane & 15, quad = lane >> 4;
    float gpart[4] = {0.f, 0.f, 0.f, 0.f};
#pragma unroll
    for (int c = 0; c < 8; ++c) {
        int col = c * 16 + li;
        float wgc = wg[col];
#pragma unroll
        for (int rr = 0; rr < 4; ++rr) {
            int m = row0 + wv * 16 + quad * 4 + rr;
            if (m < N) {
                int g = batch[m];
                float b = gb[(size_t)g * EMB + col];
                float res = x[(size_t)m * EMB + col];
                float v = lrelu(acc[c][rr] + b) + res;
                xout[(size_t)m * EMB + col] = v;
                gpart[rr] = fmaf(v, wgc, gpart[rr]);
            }
        }
    }
#pragma unroll
    for (int rr = 0; rr < 4; ++rr) {
#pragma unroll
        for (int off = 1; off < 16; off <<= 1)
            gpart[rr] += __shfl_xor(gpart[rr], off, 64);
    }
    if (li == 0) {
        float b0 = bg[0];
#pragma unroll
        for (int rr = 0; rr < 4; ++rr) {
            int m = row0 + wv * 16 + quad * 4 + rr;
            if (m < N) gate[m] = gpart[rr] + b0;
        }
    }
}

// feat16 = bf16(alpha * lrelu(x@Wfeat + bfeat))
__global__ __launch_bounds__(256) void k_gemm_feat(const float* __restrict__ A,
                                                   const unsigned short* __restrict__ Bp,
                                                   const float* __restrict__ bias,
                                                   const float* __restrict__ gate,
                                                   const float* __restrict__ gmax,
                                                   const float* __restrict__ denom,
                                                   const int* __restrict__ batch,
                                                   unsigned short* __restrict__ C, int N) {
    __shared__ unsigned short lB[16384];
    int tid = threadIdx.x, wv = tid >> 6, lane = tid & 63;
    int row0 = blockIdx.x * 64;
    stageB(Bp, lB, tid);
    bf8s af[4];
    loadAx(A, row0, wv, lane, N, af);
    __syncthreads();
    f32x4 acc[8];
#pragma unroll
    for (int c = 0; c < 8; ++c) acc[c] = (f32x4){0.f, 0.f, 0.f, 0.f};
    mfma128r(af, lB, acc, lane);
    int li = lane & 15, quad = lane >> 4;
    float alpha[4];
#pragma unroll
    for (int rr = 0; rr < 4; ++rr) {
        int m = row0 + wv * 16 + quad * 4 + rr;
        if (m < N) {
            int g = batch[m];
            alpha[rr] = __expf(gate[m] - gmax[g]) / denom[g];
        } else alpha[rr] = 0.f;
    }
#pragma unroll
    for (int c = 0; c < 8; ++c) {
        int col = c * 16 + li;
        float b = bias[col];
#pragma unroll
        for (int rr = 0; rr < 4; ++rr) {
            int m = row0 + wv * 16 + quad * 4 + rr;
            if (m < N) C[(size_t)m * EMB + col] = f2bf(alpha[rr] * lrelu(acc[c][rr] + b));
        }
    }
}

// ---------------- fused edge-message MFMA + segment-max (R5 proven version) ----------------
// One wave per node; 16-edge batches. A-frag: lane (li,oct) gathers
// ea[slot[r0+b+li].y][oct*8..+7]. 8 MFMAs vs LDS-staged Wm_e give emsg in
// C-layout (col=ci*16+li, row=oct*4+rr = edge b+oct*4+rr). Add h[src] (2B
// gather), lrelu, masked max; cheap 16-shfl epilogue (R6's transposed variant
// regressed: per-node 128-shfl reduction dominated at mean degree 8).
__global__ __launch_bounds__(256) void k_fagg(const unsigned short* __restrict__ h,
                                              const float* __restrict__ ea,
                                              const int2* __restrict__ slot,
                                              const int* __restrict__ rowptr,
                                              const unsigned short* __restrict__ Bp,
                                              unsigned short* __restrict__ agg, int N) {
    __shared__ unsigned short lB[4096];   // Wm_e: [ctile(8)][lane(64)][j(8)]
    int tid = threadIdx.x;
    ((int4*)lB)[tid]       = ((const int4*)Bp)[tid];
    ((int4*)lB)[tid + 256] = ((const int4*)Bp)[tid + 256];
    __syncthreads();
    int wv = tid >> 6, lane = tid & 63;
    int n = blockIdx.x * 4 + wv;
    if (n >= N) return;
    int li = lane & 15, oct = lane >> 4;
    int r0 = rowptr[n], r1 = rowptr[n + 1], deg = r1 - r0;

    float vm[8];
#pragma unroll
    for (int ci = 0; ci < 8; ++ci) vm[ci] = -__builtin_inff();

    for (int b = 0; b < deg; b += 16) {
        int p = r0 + b + li;
        if (p > r1 - 1) p = r1 - 1;
        int2 sl = slot[p];
        const float4* ear = (const float4*)(ea + (size_t)sl.y * EDGE);
        float4 v0 = ear[oct * 2], v1 = ear[oct * 2 + 1];
        union { bf8s v; unsigned u[4]; } ac;
        ac.u[0] = pk2bf(v0.x, v0.y);
        ac.u[1] = pk2bf(v0.z, v0.w);
        ac.u[2] = pk2bf(v1.x, v1.y);
        ac.u[3] = pk2bf(v1.z, v1.w);
        bf8s a = ac.v;
        int src_r[4]; bool val_r[4];
#pragma unroll
        for (int rr = 0; rr < 4; ++rr) {
            src_r[rr] = __shfl(sl.x, oct * 4 + rr, 16);
            val_r[rr] = (b + oct * 4 + rr) < deg;
        }
#pragma unroll
        for (int ci = 0; ci < 8; ++ci) {
            bf8s bb = *(const bf8s*)&lB[(ci * 64 + lane) * 8];
            f32x4 acc = (f32x4){0.f, 0.f, 0.f, 0.f};
            acc = __builtin_amdgcn_mfma_f32_16x16x32_bf16(a, bb, acc, 0, 0, 0);
            int col = ci * 16 + li;
#pragma unroll
            for (int rr = 0; rr < 4; ++rr) {
                float hv = bf2f(h[(size_t)src_r[rr] * EMB + col]);
                float t = lrelu(hv + acc[rr]);
                if (val_r[rr]) vm[ci] = fmaxf(vm[ci], t);
            }
        }
    }
#pragma unroll
    for (int ci = 0; ci < 8; ++ci) {
        vm[ci] = fmaxf(vm[ci], __shfl_xor(vm[ci], 16, 64));
        vm[ci] = fmaxf(vm[ci], __shfl_xor(vm[ci], 32, 64));
    }
    float s0 = (oct == 0) ? vm[0] : (oct == 1) ? vm[1] : (oct == 2) ? vm[2] : vm[3];
    float s1 = (oct == 0) ? vm[4] : (oct == 1) ? vm[5] : (oct == 2) ? vm[6] : vm[7];
    if (deg == 0) { s0 = 0.f; s1 = 0.f; }
    agg[(size_t)n * EMB + oct * 16 + li]        = f2bf(s0);
    agg[(size_t)n * EMB + (oct + 4) * 16 + li]  = f2bf(s1);
}

// ---------------- small per-graph kernels ----------------
__global__ __launch_bounds__(128) void k_gb(const float* __restrict__ xg,
                                            const float* __restrict__ WaG,
                                            const float* __restrict__ ba,
                                            float* __restrict__ gb) {
    int g = blockIdx.x, c = threadIdx.x;
    __shared__ float row[EMB];
    row[c] = xg[(size_t)g * EMB + c];
    __syncthreads();
    float acc = ba[c];
#pragma unroll 8
    for (int k = 0; k < EMB; ++k) acc = fmaf(row[k], WaG[(size_t)k * EMB + c], acc);
    gb[(size_t)g * EMB + c] = acc;
}

__global__ __launch_bounds__(256) void k_gseg(const float* __restrict__ gate,
                                              const int* __restrict__ gstart,
                                              float* __restrict__ gmax,
                                              float* __restrict__ denom) {
    int g = blockIdx.x;
    int s0 = gstart[g], s1 = gstart[g + 1];
    __shared__ float red[256];
    int t = threadIdx.x;
    float mx = -__builtin_inff();
    for (int i = s0 + t; i < s1; i += 256) mx = fmaxf(mx, gate[i]);
    red[t] = mx;
    __syncthreads();
#pragma unroll
    for (int off = 128; off; off >>= 1) {
        if (t < off) red[t] = fmaxf(red[t], red[t + off]);
        __syncthreads();
    }
    float m = red[0];
    __syncthreads();
    float sum = 0.f;
    for (int i = s0 + t; i < s1; i += 256) sum += __expf(gate[i] - m);
    red[t] = sum;
    __syncthreads();
#pragma unroll
    for (int off = 128; off; off >>= 1) {
        if (t < off) red[t] += red[t + off];
        __syncthreads();
    }
    if (t == 0) {
        gmax[g] = (s1 > s0) ? m : 0.f;
        denom[g] = red[0];
    }
}

__global__ __launch_bounds__(512) void k_pool(const unsigned short* __restrict__ feat,
                                              const int* __restrict__ gstart,
                                              float* __restrict__ pooled) {
    int g = blockIdx.x;
    int c = threadIdx.x & 127;
    int r = threadIdx.x >> 7;
    int s0 = gstart[g], s1 = gstart[g + 1];
    float s = 0.f;
    for (int i = s0 + r; i < s1; i += 4) s += bf2f(feat[(size_t)i * EMB + c]);
    __shared__ float red[512];
    red[threadIdx.x] = s;
    __syncthreads();
    if (threadIdx.x < 256) red[threadIdx.x] += red[threadIdx.x + 256];
    __syncthreads();
    if (threadIdx.x < 128)
        pooled[(size_t)g * EMB + threadIdx.x] = red[threadIdx.x] + red[threadIdx.x + 128];
}

__global__ __launch_bounds__(128) void k_xg(const float* __restrict__ pooled,
                                            const float* __restrict__ xg,
                                            const float* __restrict__ Wt,
                                            const float* __restrict__ bt,
                                            float* __restrict__ xg_out) {
    int g = blockIdx.x, c = threadIdx.x;
    __shared__ float row[256];
    row[c] = pooled[(size_t)g * EMB + c];
    row[c + 128] = xg[(size_t)g * EMB + c];
    __syncthreads();
    float acc = bt[c];
#pragma unroll 8
    for (int k = 0; k < 256; ++k) acc = fmaf(row[k], Wt[(size_t)k * EMB + c], acc);
    xg_out[(size_t)g * EMB + c] = lrelu(acc) + row[c + 128];
}

// ---------------- launch ----------------
extern "C" void kernel_launch(void* const* d_in, const int* in_sizes, int n_in,
                              void* d_out, int out_size, void* d_ws, size_t ws_size,
                              hipStream_t stream) {
    const float* x0    = (const float*)d_in[0];
    const float* ea    = (const float*)d_in[1];
    const float* Wm    = (const float*)d_in[2];
    const float* bm    = (const float*)d_in[3];
    const float* Wa    = (const float*)d_in[4];
    const float* ba    = (const float*)d_in[5];
    const float* Wgate = (const float*)d_in[6];
    const float* bgate = (const float*)d_in[7];
    const float* Wfeat = (const float*)d_in[8];
    const float* bfeat = (const float*)d_in[9];
    const float* Wt    = (const float*)d_in[10];
    const float* bt    = (const float*)d_in[11];
    const int*   eidx  = (const int*)d_in[12];
    const int*   batch = (const int*)d_in[13];

    int N = in_sizes[0] / EMB;
    int E = in_sizes[1] / EDGE;
    int G = in_sizes[15];

    char* w = (char*)d_ws;
    auto alloc = [&](size_t bytes) {
        char* p = w;
        w += (bytes + 255) & ~(size_t)255;
        return p;
    };
    unsigned short* h16   = (unsigned short*)alloc((size_t)N * EMB * 2);
    unsigned short* agg16 = (unsigned short*)alloc((size_t)N * EMB * 2);
    unsigned short* ft16  = (unsigned short*)alloc((size_t)N * EMB * 2);
    float* gate   = (float*)alloc((size_t)N * 4);
    float* gb     = (float*)alloc((size_t)G * EMB * 4);
    float* pooled = (float*)alloc((size_t)G * EMB * 4);
    float* gmax   = (float*)alloc((size_t)G * 4);
    float* denom  = (float*)alloc((size_t)G * 4);
    float* xg_a   = (float*)alloc((size_t)G * EMB * 4);
    float* xg_b   = (float*)alloc((size_t)G * EMB * 4);
    int* deg      = (int*)alloc((size_t)N * 4);
    int* rowptr   = (int*)alloc((size_t)(N + 1) * 4);
    int* cursor   = (int*)alloc((size_t)N * 4);
    int2* slot    = (int2*)alloc((size_t)E * 8);
    int* gstart   = (int*)alloc((size_t)(G + 1) * 4);
    int* bsums    = (int*)alloc(1024 * 4);
    unsigned short* wpack = (unsigned short*)alloc((size_t)15 * 16384 * 2);

    const int* esrc = eidx;
    const int* edst = eidx + E;
    int ebl = (E + 255) / 256;
    int NB  = (N + 255) / 256;

    hipMemsetAsync(deg, 0, (size_t)N * 4, stream);
    k_hist<<<ebl, 256, 0, stream>>>(edst, E, deg);
    k_scan1<<<NB, 256, 0, stream>>>(deg, N, rowptr, bsums);
    k_scan2<<<1, 256, 0, stream>>>(bsums, NB);
    k_scan3<<<NB, 256, 0, stream>>>(rowptr, bsums, N, E);
    hipMemcpyAsync(cursor, rowptr, (size_t)N * 4, hipMemcpyDeviceToDevice, stream);
    k_fill<<<ebl, 256, 0, stream>>>(esrc, edst, E, cursor, slot);
    k_gstart<<<(G + 256) / 256, 256, 0, stream>>>(batch, N, G, gstart);
    hipMemsetAsync(xg_a, 0, (size_t)G * EMB * 4, stream);
    k_wpack<<<960, 256, 0, stream>>>(Wm, Wa, Wfeat, wpack);

    int gemm_blocks = (N + 63) / 64;
    int fagg_blocks = (N + 3) / 4;

    const float* x_in = x0;
    float* xg_cur = xg_a;
    float* xg_nxt = xg_b;

    for (int s = 0; s < STEPS; ++s) {
        const unsigned short* wp = wpack + (size_t)s * 5 * 16384;
        float* x_out = (s == STEPS - 1) ? (float*)d_out : (float*)x_in;

        k_gemm_bias<<<gemm_blocks, 256, 0, stream>>>(x_in, wp + 0 * 16384, bm + s * EMB,
                                                     h16, N);
        k_fagg<<<fagg_blocks, 256, 0, stream>>>(h16, ea, slot, rowptr, wp + 1 * 16384,
                                                agg16, N);
        k_gb<<<G, 128, 0, stream>>>(xg_cur, Wa + (size_t)s * 384 * EMB + 128 * EMB,
                                    ba + s * EMB, gb);
        k_gemm_node<<<gemm_blocks, 256, 0, stream>>>(x_in, agg16, wp + 2 * 16384,
                                                     wp + 3 * 16384, gb, batch, x_out,
                                                     Wgate + s * EMB, bgate + s, gate, N);
        k_gseg<<<G, 256, 0, stream>>>(gate, gstart, gmax, denom);
        k_gemm_feat<<<gemm_blocks, 256, 0, stream>>>(x_out, wp + 4 * 16384, bfeat + s * EMB,
                                                     gate, gmax, denom, batch, ft16, N);
        k_pool<<<G, 512, 0, stream>>>(ft16, gstart, pooled);
        k_xg<<<G, 128, 0, stream>>>(pooled, xg_cur, Wt + (size_t)s * 256 * EMB,
                                    bt + s * EMB, xg_nxt);

        x_in = x_out;
        float* tmp = xg_cur; xg_cur = xg_nxt; xg_nxt = tmp;
    }

    hipMemcpyAsync((float*)d_out + (size_t)N * EMB, xg_cur, (size_t)G * EMB * 4,
                   hipMemcpyDeviceToDevice, stream);
}